// Round 1
// baseline (249.016 us; speedup 1.0000x reference)
//
#include <hip/hip_runtime.h>
#include <hip/hip_bf16.h>
#include <math.h>

// Problem constants (fixed by reference).
constexpr int NVOX = 40000;
constexpr int NQRY = 8192;
constexpr int KK   = 96;
constexpr int CH   = 128;
constexpr int FFD  = 256;
constexpr int NKVB = (NVOX/64)*8;   // 5000 fused LN+KV blocks, bx&7 = head

typedef __attribute__((ext_vector_type(8))) short short8;
typedef __attribute__((ext_vector_type(4))) float float4v;

__device__ inline float bflo(unsigned u) { return __uint_as_float(u << 16); }
__device__ inline float bfhi(unsigned u) { return __uint_as_float(u & 0xffff0000u); }
__device__ inline unsigned short f2bf(float x) {
  union { float f; unsigned u; } a; a.f = x;
  const unsigned r = a.u + 0x7fffu + ((a.u >> 16) & 1u);  // round-to-nearest-even
  return (unsigned short)(r >> 16);
}
__device__ inline unsigned pack2(float lo, float hi) {
  return (unsigned)f2bf(lo) | ((unsigned)f2bf(hi) << 16);
}

// ---------------------------------------------------------------------------
// Kernel 1 (fused): one launch does everything the attention needs.
//  blocks [0, NKVB):            per-voxel LN + relu(key-pos) computed INLINE
//                               in MFMA A-fragment layout (no Gb round-trip),
//                               B-frags converted bf16 inline from f32 in_w,
//                               KV GEMM -> KVh. bx&7 = head (XCD pinning
//                               matches k_attn).
//  blocks [NKVB, NKVB+24):      epilogue weights -> Eb bf16
//  blocks [NKVB+24, +512):      q = relu(qc@q_pos_w.T+b) @ wq.T + bq -> qb f32
// ---------------------------------------------------------------------------
__global__ __launch_bounds__(256) void k_main(
    const float* __restrict__ vfeat, const float* __restrict__ vcoord,
    const float* __restrict__ n1g, const float* __restrict__ n1b,
    const float* __restrict__ kpw, const float* __restrict__ kpb,
    const float* __restrict__ in_w, const float* __restrict__ in_b,
    const float* __restrict__ ow, const float* __restrict__ l1w,
    const float* __restrict__ l2w, const float* __restrict__ fw,
    const float* __restrict__ qcoord,
    const float* __restrict__ qpw, const float* __restrict__ qpb,
    unsigned short* __restrict__ KVh, __hip_bfloat16* __restrict__ Eb,
    float* __restrict__ qout) {
  const int b = blockIdx.x;
  const int t = threadIdx.x;
  if (b < NKVB) {
    __shared__ unsigned short ldsD[64][40];   // 32 data + 8 pad
    const int w    = t >> 6;
    const int lane = t & 63;
    const int col  = lane & 15;
    const int quad = lane >> 4;
    const int h    = b & 7;
    const int v0   = (b >> 3) * 64;
    const int j    = v0 + w*16 + col;          // this lane-group's voxel row

    // ---- inline LayerNorm + relu(key-pos): produce A-fragments directly ----
    const float* vrow = vfeat + (size_t)j * CH;
    float xv[4][8];
    float s = 0.0f, ss = 0.0f;
    #pragma unroll
    for (int kq = 0; kq < 4; kq++) {
      const float4 a = *reinterpret_cast<const float4*>(vrow + kq*32 + quad*8);
      const float4 c = *reinterpret_cast<const float4*>(vrow + kq*32 + quad*8 + 4);
      xv[kq][0]=a.x; xv[kq][1]=a.y; xv[kq][2]=a.z; xv[kq][3]=a.w;
      xv[kq][4]=c.x; xv[kq][5]=c.y; xv[kq][6]=c.z; xv[kq][7]=c.w;
      s  += a.x+a.y+a.z+a.w + c.x+c.y+c.z+c.w;
      ss += a.x*a.x+a.y*a.y+a.z*a.z+a.w*a.w
          + c.x*c.x+c.y*c.y+c.z*c.z+c.w*c.w;
    }
    // the 4 quads of one voxel live in lanes {col, col+16, col+32, col+48}
    s += __shfl_xor(s, 16);  ss += __shfl_xor(ss, 16);
    s += __shfl_xor(s, 32);  ss += __shfl_xor(ss, 32);
    const float mean = s * (1.0f/CH);
    const float var  = ss * (1.0f/CH) - mean*mean;
    const float rstd = 1.0f / sqrtf(var + 1e-5f);
    const float c0 = vcoord[j*3+0], c1 = vcoord[j*3+1], c2 = vcoord[j*3+2];
    short8 afrag[4];
    #pragma unroll
    for (int kq = 0; kq < 4; kq++) {
      const int cb = kq*32 + quad*8;
      const float4 g0 = *reinterpret_cast<const float4*>(n1g + cb);
      const float4 g1 = *reinterpret_cast<const float4*>(n1g + cb + 4);
      const float4 be0 = *reinterpret_cast<const float4*>(n1b + cb);
      const float4 be1 = *reinterpret_cast<const float4*>(n1b + cb + 4);
      const float4 p0 = *reinterpret_cast<const float4*>(kpb + cb);
      const float4 p1 = *reinterpret_cast<const float4*>(kpb + cb + 4);
      float kw[24];
      #pragma unroll
      for (int q2 = 0; q2 < 6; q2++) {
        const float4 f = *reinterpret_cast<const float4*>(kpw + cb*3 + q2*4);
        kw[q2*4+0]=f.x; kw[q2*4+1]=f.y; kw[q2*4+2]=f.z; kw[q2*4+3]=f.w;
      }
      const float gam[8]  = {g0.x,g0.y,g0.z,g0.w,g1.x,g1.y,g1.z,g1.w};
      const float bet[8]  = {be0.x,be0.y,be0.z,be0.w,be1.x,be1.y,be1.z,be1.w};
      const float kpbv[8] = {p0.x,p0.y,p0.z,p0.w,p1.x,p1.y,p1.z,p1.w};
      short8 af;
      #pragma unroll
      for (int u = 0; u < 8; u++) {
        const float vf = (xv[kq][u] - mean) * rstd * gam[u] + bet[u];
        const float kp = fmaf(c0, kw[u*3+0],
                         fmaf(c1, kw[u*3+1],
                         fmaf(c2, kw[u*3+2], kpbv[u])));
        af[u] = (short)f2bf(vf + fmaxf(kp, 0.0f));
      }
      afrag[kq] = af;
    }

    // ---- B fragments converted inline from f32 KV weights; MFMA ----
    const float biaK = in_b[CH   + h*16 + col];
    const float biaV = in_b[2*CH + h*16 + col];
    float4v accK = (float4v){biaK, biaK, biaK, biaK};
    float4v accV = (float4v){biaV, biaV, biaV, biaV};
    const float* wK = in_w + (size_t)(CH   + h*16 + col)*CH;
    const float* wV = in_w + (size_t)(2*CH + h*16 + col)*CH;
    #pragma unroll
    for (int kq = 0; kq < 4; kq++) {
      const float4 k0 = *reinterpret_cast<const float4*>(wK + kq*32 + quad*8);
      const float4 k1 = *reinterpret_cast<const float4*>(wK + kq*32 + quad*8 + 4);
      short8 bK;
      bK[0]=(short)f2bf(k0.x); bK[1]=(short)f2bf(k0.y);
      bK[2]=(short)f2bf(k0.z); bK[3]=(short)f2bf(k0.w);
      bK[4]=(short)f2bf(k1.x); bK[5]=(short)f2bf(k1.y);
      bK[6]=(short)f2bf(k1.z); bK[7]=(short)f2bf(k1.w);
      accK = __builtin_amdgcn_mfma_f32_16x16x32_bf16(afrag[kq], bK, accK, 0, 0, 0);
      const float4 u0 = *reinterpret_cast<const float4*>(wV + kq*32 + quad*8);
      const float4 u1 = *reinterpret_cast<const float4*>(wV + kq*32 + quad*8 + 4);
      short8 bV;
      bV[0]=(short)f2bf(u0.x); bV[1]=(short)f2bf(u0.y);
      bV[2]=(short)f2bf(u0.z); bV[3]=(short)f2bf(u0.w);
      bV[4]=(short)f2bf(u1.x); bV[5]=(short)f2bf(u1.y);
      bV[6]=(short)f2bf(u1.z); bV[7]=(short)f2bf(u1.w);
      accV = __builtin_amdgcn_mfma_f32_16x16x32_bf16(afrag[kq], bV, accV, 0, 0, 0);
    }
    #pragma unroll
    for (int r = 0; r < 4; r++) {
      const int row = w*16 + quad*4 + r;
      ldsD[row][col]      = f2bf(accK[r]);
      ldsD[row][16 + col] = f2bf(accV[r]);
    }
    __syncthreads();
    const int v  = t >> 2;
    const int qq = t & 3;
    const uint4 d = *reinterpret_cast<const uint4*>(&ldsD[v][qq*8]);
    *reinterpret_cast<uint4*>(KVh + ((size_t)h*NVOX + v0 + v)*32 + qq*8) = d;
  } else if (b < NKVB + 24) {
    // epilogue weights -> bf16
    const int idx = b - NKVB;
    const int f = (idx * 256 + t) * 16;   // 0..98303
    const float* src;
    __hip_bfloat16* dst = Eb + f;
    if      (f < 16384) src = ow  + f;
    else if (f < 49152) src = l1w + (f - 16384);
    else if (f < 81920) src = l2w + (f - 49152);
    else                src = fw  + (f - 81920);
    float v[16];
    #pragma unroll
    for (int u = 0; u < 4; u++) {
      const float4 fq = *reinterpret_cast<const float4*>(src + u*4);
      v[u*4+0]=fq.x; v[u*4+1]=fq.y; v[u*4+2]=fq.z; v[u*4+3]=fq.w;
    }
    uint4* o = reinterpret_cast<uint4*>(dst);
    o[0] = make_uint4(pack2(v[0],v[1]), pack2(v[2],v[3]),
                      pack2(v[4],v[5]), pack2(v[6],v[7]));
    o[1] = make_uint4(pack2(v[8],v[9]), pack2(v[10],v[11]),
                      pack2(v[12],v[13]), pack2(v[14],v[15]));
  } else {
    // q projection: 16 queries per block.
    __shared__ float qf[16][CH];
    const int qbase = (b - (NKVB + 24)) * 16;
    #pragma unroll
    for (int i = 0; i < 8; i++) {
      const int e = t + 256*i;
      const int qv = e >> 7, c = e & 127;
      const int qq = qbase + qv;
      const float v = fmaf(qcoord[qq*3+0], qpw[c*3+0],
                      fmaf(qcoord[qq*3+1], qpw[c*3+1],
                      fmaf(qcoord[qq*3+2], qpw[c*3+2], qpb[c])));
      qf[qv][c] = fmaxf(v, 0.0f);
    }
    __syncthreads();
    const int oc = t & 127, half = t >> 7;
    const float* wrow = in_w + (size_t)oc * CH;
    const float bia = in_b[oc];
    float acc[8];
    #pragma unroll
    for (int v = 0; v < 8; v++) acc[v] = bia;
    for (int c = 0; c < CH; c += 4) {
      const float4 w4 = *reinterpret_cast<const float4*>(wrow + c);
      #pragma unroll
      for (int v = 0; v < 8; v++) {
        const float4 g4 = *reinterpret_cast<const float4*>(&qf[half*8+v][c]);
        acc[v] = fmaf(g4.x, w4.x, fmaf(g4.y, w4.y, fmaf(g4.z, w4.z, fmaf(g4.w, w4.w, acc[v]))));
      }
    }
    #pragma unroll
    for (int v = 0; v < 8; v++) qout[(size_t)(qbase + half*8 + v)*CH + oc] = acc[v];
  }
}

// ---------------------------------------------------------------------------
// Kernel 3: attention with FUSED L2 warm prologue (unchanged). Block = (8q,1h);
// blockIdx.x = qg*8 + h (head<->XCD pinning matches k_main's KV blocks).
// ---------------------------------------------------------------------------
__global__ __launch_bounds__(256) void k_attn(
    const unsigned short* __restrict__ KVh,
    const float* __restrict__ qg, const int* __restrict__ kidx,
    float* __restrict__ ctxg, unsigned* __restrict__ sink) {
  __shared__ float qs[8][16];
  __shared__ float sc[8*104];     // stride 104: conflict-free softmax/ctx reads
  __shared__ float red[128][9];   // slot-padded ctx partials
  __shared__ float rden[8];
  const int t    = threadIdx.x;
  const int h    = blockIdx.x & 7;
  const int n0   = (blockIdx.x >> 3) * 8;
  const int w    = t >> 6;
  const int lane = t & 63;
  const int quad = lane >> 2;     // 0..15
  const int r    = lane & 3;      // lane role within quad
  const int qh   = quad >> 3;     // 0/1: which of the wave's 2 queries
  const int g    = quad & 7;      // key slot group: keys g, g+8, ..., g+88
  const int q_l  = 2*w + qh;      // block-local query 0..7
  const unsigned short* KVbase = KVh + (size_t)h * NVOX * 32;

  // Fused warm: stream 40 sequential lines of this head's slice (overlapped).
  uint4 wv = make_uint4(0u, 0u, 0u, 0u);
  if (t < 40) {
    int line = (blockIdx.x >> 3) * 39 + t;
    if (line > NVOX - 1) line = NVOX - 1;
    wv = *reinterpret_cast<const uint4*>(KVbase + (size_t)line * 32);
  }

  if (t < 128) {
    const int q = t >> 4, d = t & 15;
    qs[q][d] = qg[(size_t)(n0 + q)*CH + h*16 + d];
  }
  // Loads: 12 keys per quad; each lane fetches its 16-B quarter of the line.
  unsigned msk = 0;
  uint4 kvbuf[12];
  const int krow = (n0 + q_l)*KK + g;
  #pragma unroll
  for (int it = 0; it < 12; it++) {
    const int j0 = kidx[krow + it*8];
    msk |= (unsigned)(j0 < 0) << it;
    const int j = (j0 < 0) ? 0 : j0;   // clamp like reference
    kvbuf[it] = *reinterpret_cast<const uint4*>(KVbase + (size_t)j*32 + r*8);
  }
  __syncthreads();
  // Scores: r0/r1 lanes hold K halves; q half selected by r&1.
  const float4 qa = *reinterpret_cast<const float4*>(&qs[q_l][(r & 1)*8]);
  const float4 qb = *reinterpret_cast<const float4*>(&qs[q_l][(r & 1)*8 + 4]);
  #pragma unroll
  for (int it = 0; it < 12; it++) {
    const uint4 kv = kvbuf[it];
    float s = 0.0f;
    s = fmaf(qa.x, bflo(kv.x), s); s = fmaf(qa.y, bfhi(kv.x), s);
    s = fmaf(qa.z, bflo(kv.y), s); s = fmaf(qa.w, bfhi(kv.y), s);
    s = fmaf(qb.x, bflo(kv.z), s); s = fmaf(qb.y, bfhi(kv.z), s);
    s = fmaf(qb.z, bflo(kv.w), s); s = fmaf(qb.w, bfhi(kv.w), s);
    s += __shfl_xor(s, 1);          // r0+r1 (K full dot); r2+r3 garbage unused
    if (r == 0)
      sc[q_l*104 + g + it*8] = ((msk >> it) & 1) ? -1e9f : s * 0.25f;
  }
  __syncthreads();
  // Softmax per query: 16 lanes over 96 keys.
  if (t < 128) {
    const int q = t >> 4, l = t & 15;
    float mx = -3e38f;
    #pragma unroll
    for (int k = l; k < KK; k += 16) mx = fmaxf(mx, sc[q*104 + k]);
    #pragma unroll
    for (int m = 8; m >= 1; m >>= 1) mx = fmaxf(mx, __shfl_xor(mx, m));
    float sum = 0.0f;
    #pragma unroll
    for (int k = l; k < KK; k += 16) {
      const float p = __expf(sc[q*104 + k] - mx);   // masked -> exactly 0
      sc[q*104 + k] = p;
      sum += p;
    }
    #pragma unroll
    for (int m = 8; m >= 1; m >>= 1) sum += __shfl_xor(sum, m);
    if (l == 0) rden[q] = 1.0f / sum;
  }
  __syncthreads();
  // ctx: r2/r3 lanes accumulate their V half over their 12 keys.
  {
    float acc[8] = {0,0,0,0,0,0,0,0};
    #pragma unroll
    for (int it = 0; it < 12; it++) {
      const float wg = sc[q_l*104 + g + it*8];   // broadcast within quad
      const uint4 kv = kvbuf[it];
      acc[0] = fmaf(wg, bflo(kv.x), acc[0]); acc[1] = fmaf(wg, bfhi(kv.x), acc[1]);
      acc[2] = fmaf(wg, bflo(kv.y), acc[2]); acc[3] = fmaf(wg, bfhi(kv.y), acc[3]);
      acc[4] = fmaf(wg, bflo(kv.z), acc[4]); acc[5] = fmaf(wg, bfhi(kv.z), acc[5]);
      acc[6] = fmaf(wg, bflo(kv.w), acc[6]); acc[7] = fmaf(wg, bfhi(kv.w), acc[7]);
    }
    if (r >= 2) {
      const int slot = q_l*16 + g*2 + (r - 2);   // 0..127
      #pragma unroll
      for (int u = 0; u < 8; u++) red[slot][u] = acc[u];
    }
  }
  __syncthreads();
  // Reduce 8 slot-groups per (query, channel) and store.
  if (t < 128) {
    const int q = t >> 4, d = t & 15;
    const int half = d >> 3, u = d & 7;
    float s = 0.0f;
    #pragma unroll
    for (int gg = 0; gg < 8; gg++) s += red[q*16 + gg*2 + half][u];
    ctxg[(size_t)(n0 + q)*CH + h*16 + d] = s * rden[q];
  }
  // Warm-load consumption (impossible condition; waitcnt lands here, after
  // all useful work, so the warm never stalls the block).
  const unsigned accw = wv.x ^ wv.y ^ wv.z ^ wv.w;
  if (accw == 0x9E3779B9u && t == 255) sink[0] = accw;
}

// ---------------------------------------------------------------------------
// Kernel 4: epilogue via MFMA bf16 (unchanged).
// ---------------------------------------------------------------------------
__global__ __launch_bounds__(256) void k_epi(
    const float* __restrict__ ctxg, const __hip_bfloat16* __restrict__ Eb,
    const float* __restrict__ ob,
    const float* __restrict__ n2g, const float* __restrict__ n2b,
    const float* __restrict__ l1b, const float* __restrict__ l2b,
    const float* __restrict__ fb,
    float* __restrict__ outp) {
  __shared__ unsigned short csb[16][136];
  __shared__ float attnS[16][132];
  __shared__ unsigned short hb[16][136];
  __shared__ unsigned short a1b[16][264];
  __shared__ unsigned short xb[16][136];
  const unsigned short* owb  = reinterpret_cast<const unsigned short*>(Eb);
  const unsigned short* l1wb = owb + 16384;
  const unsigned short* l2wb = owb + 49152;
  const unsigned short* fwb  = owb + 81920;

  const int t = threadIdx.x;
  const int w = t >> 6;
  const int lane = t & 63;
  const int col = lane & 15;
  const int quad = lane >> 4;
  const int qbase = blockIdx.x * 16;

  {
    const int e = t * 8;
    const int row = e >> 7, cc = e & 127;
    const float4* src = reinterpret_cast<const float4*>(ctxg + (size_t)(qbase+row)*CH + cc);
    const float4 x0 = src[0], x1 = src[1];
    *reinterpret_cast<uint4*>(&csb[row][cc]) =
        make_uint4(pack2(x0.x,x0.y), pack2(x0.z,x0.w), pack2(x1.x,x1.y), pack2(x1.z,x1.w));
  }
  __syncthreads();
  {
    short8 af[4];
    #pragma unroll
    for (int kq = 0; kq < 4; kq++)
      af[kq] = *reinterpret_cast<const short8*>(&csb[col][quad*8 + kq*32]);
    #pragma unroll
    for (int j = 0; j < 2; j++) {
      const int n0 = w*32 + j*16;
      const float bia = ob[n0 + col];
      float4v acc = (float4v){bia, bia, bia, bia};
      #pragma unroll
      for (int kq = 0; kq < 4; kq++) {
        const short8 bf = *reinterpret_cast<const short8*>(
            owb + (size_t)(n0 + col)*CH + kq*32 + quad*8);
        acc = __builtin_amdgcn_mfma_f32_16x16x32_bf16(af[kq], bf, acc, 0, 0, 0);
      }
      #pragma unroll
      for (int r = 0; r < 4; r++) attnS[quad*4 + r][n0 + col] = acc[r];
    }
  }
  __syncthreads();
  {
    const int row = t >> 4, l = t & 15;
    float s = 0.0f, ss = 0.0f;
    #pragma unroll
    for (int c = l; c < CH; c += 16) { const float x = attnS[row][c]; s += x; ss += x*x; }
    #pragma unroll
    for (int m = 8; m >= 1; m >>= 1) { s += __shfl_xor(s, m); ss += __shfl_xor(ss, m); }
    const float mean = s * (1.0f/CH);
    const float var  = ss * (1.0f/CH) - mean*mean;
    const float rstd = 1.0f / sqrtf(var + 1e-5f);
    #pragma unroll
    for (int c = l; c < CH; c += 16)
      hb[row][c] = f2bf((attnS[row][c] - mean) * rstd * n2g[c] + n2b[c]);
  }
  __syncthreads();
  {
    short8 af[4];
    #pragma unroll
    for (int kq = 0; kq < 4; kq++)
      af[kq] = *reinterpret_cast<const short8*>(&hb[col][quad*8 + kq*32]);
    #pragma unroll
    for (int j = 0; j < 4; j++) {
      const int n0 = w*64 + j*16;
      const float bia = l1b[n0 + col];
      float4v acc = (float4v){bia, bia, bia, bia};
      #pragma unroll
      for (int kq = 0; kq < 4; kq++) {
        const short8 bf = *reinterpret_cast<const short8*>(
            l1wb + (size_t)(n0 + col)*CH + kq*32 + quad*8);
        acc = __builtin_amdgcn_mfma_f32_16x16x32_bf16(af[kq], bf, acc, 0, 0, 0);
      }
      #pragma unroll
      for (int r = 0; r < 4; r++)
        a1b[quad*4 + r][n0 + col] = f2bf(fmaxf(acc[r], 0.0f));
    }
  }
  __syncthreads();
  {
    short8 af[8];
    #pragma unroll
    for (int kq = 0; kq < 8; kq++)
      af[kq] = *reinterpret_cast<const short8*>(&a1b[col][quad*8 + kq*32]);
    #pragma unroll
    for (int j = 0; j < 2; j++) {
      const int n0 = w*32 + j*16;
      const float bia = l2b[n0 + col];
      float4v acc = (float4v){bia, bia, bia, bia};
      #pragma unroll
      for (int kq = 0; kq < 8; kq++) {
        const short8 bf = *reinterpret_cast<const short8*>(
            l2wb + (size_t)(n0 + col)*FFD + kq*32 + quad*8);
        acc = __builtin_amdgcn_mfma_f32_16x16x32_bf16(af[kq], bf, acc, 0, 0, 0);
      }
      #pragma unroll
      for (int r = 0; r < 4; r++)
        xb[quad*4 + r][n0 + col] = f2bf(acc[r] + attnS[quad*4 + r][n0 + col]);
    }
  }
  __syncthreads();
  {
    short8 af[4];
    #pragma unroll
    for (int kq = 0; kq < 4; kq++)
      af[kq] = *reinterpret_cast<const short8*>(&xb[col][quad*8 + kq*32]);
    #pragma unroll
    for (int j = 0; j < 2; j++) {
      const int n0 = w*32 + j*16;
      const float bia = fb[n0 + col];
      float4v acc = (float4v){bia, bia, bia, bia};
      #pragma unroll
      for (int kq = 0; kq < 4; kq++) {
        const short8 bf = *reinterpret_cast<const short8*>(
            fwb + (size_t)(n0 + col)*CH + kq*32 + quad*8);
        acc = __builtin_amdgcn_mfma_f32_16x16x32_bf16(af[kq], bf, acc, 0, 0, 0);
      }
      #pragma unroll
      for (int r = 0; r < 4; r++)
        outp[(size_t)(qbase + quad*4 + r)*CH + n0 + col] = fmaxf(acc[r], 0.0f);
    }
  }
}

// ---------------------------------------------------------------------------
extern "C" void kernel_launch(void* const* d_in, const int* in_sizes, int n_in,
                              void* d_out, int out_size, void* d_ws, size_t ws_size,
                              hipStream_t stream) {
  const float* vfeat  = (const float*)d_in[0];
  const float* vcoord = (const float*)d_in[1];
  const float* qcoord = (const float*)d_in[2];
  const int*   kidx   = (const int*)  d_in[3];
  const float* n1g    = (const float*)d_in[4];
  const float* n1b    = (const float*)d_in[5];
  const float* qpw    = (const float*)d_in[6];
  const float* qpb    = (const float*)d_in[7];
  const float* kpw    = (const float*)d_in[8];
  const float* kpb    = (const float*)d_in[9];
  const float* in_w   = (const float*)d_in[10];
  const float* in_b   = (const float*)d_in[11];
  const float* out_w  = (const float*)d_in[12];
  const float* out_b  = (const float*)d_in[13];
  const float* n2g    = (const float*)d_in[14];
  const float* n2b    = (const float*)d_in[15];
  const float* l1w    = (const float*)d_in[16];
  const float* l1b    = (const float*)d_in[17];
  const float* l2w    = (const float*)d_in[18];
  const float* l2b    = (const float*)d_in[19];
  const float* fw     = (const float*)d_in[20];
  const float* fb     = (const float*)d_in[21];
  float* out = (float*)d_out;

  unsigned short* KVh = (unsigned short*)d_ws;               // 8*NVOX*32 shorts (20.5 MB)
  __hip_bfloat16* Eb = (__hip_bfloat16*)(KVh + (size_t)8*NVOX*32);  // 98304 bf16 epi weights
  float* qb = (float*)(Eb + 98304);                          // NQRY*CH f32
  float* cx = qb + (size_t)NQRY*CH;                          // NQRY*CH f32
  unsigned* sink = (unsigned*)(cx + (size_t)NQRY*CH);        // 1 dword DCE guard

  k_main<<<NKVB + 24 + NQRY/16, 256, 0, stream>>>(
      vfeat, vcoord, n1g, n1b, kpw, kpb, in_w, in_b,
      out_w, l1w, l2w, fw, qcoord, qpw, qpb, KVh, Eb, qb);
  k_attn<<<(NQRY/8)*8, 256, 0, stream>>>(KVh, qb, kidx, cx, sink);
  k_epi <<<NQRY/16, 256, 0, stream>>>(cx, Eb, out_b, n2g, n2b, l1b, l2b, fb, out);
}

// Round 2
// 199.314 us; speedup vs baseline: 1.2494x; 1.2494x over previous
//
#include <hip/hip_runtime.h>
#include <hip/hip_bf16.h>
#include <math.h>

// Problem constants (fixed by reference).
constexpr int NVOX = 40000;
constexpr int NQRY = 8192;
constexpr int KK   = 96;
constexpr int CH   = 128;
constexpr int FFD  = 256;
constexpr int NKV  = NVOX / 64;        // 625 fused LN+KV blocks (all 8 heads each)
constexpr int NEB  = 24;               // epilogue-weight convert blocks

typedef __attribute__((ext_vector_type(8))) short short8;
typedef __attribute__((ext_vector_type(4))) float float4v;

__device__ inline float bflo(unsigned u) { return __uint_as_float(u << 16); }
__device__ inline float bfhi(unsigned u) { return __uint_as_float(u & 0xffff0000u); }
__device__ inline unsigned short f2bf(float x) {
  union { float f; unsigned u; } a; a.f = x;
  const unsigned r = a.u + 0x7fffu + ((a.u >> 16) & 1u);  // round-to-nearest-even
  return (unsigned short)(r >> 16);
}
__device__ inline unsigned pack2(float lo, float hi) {
  return (unsigned)f2bf(lo) | ((unsigned)f2bf(hi) << 16);
}

// ---------------------------------------------------------------------------
// Kernel 1 (fused, redundancy-free):
//  blocks [0, NKV):        64 voxels: LN+relu(key-pos) ONCE -> swizzled LDS
//                          tile; then 4 warps x 2 heads: KV GEMM via MFMA with
//                          B-frags converted inline from f32 in_w. -> KVh.
//  blocks [NKV, NKV+24):   epilogue weights -> Eb bf16
//  blocks [NKV+24, +512):  q = relu(qc@q_pos_w.T+b) @ wq.T + bq -> qb f32
// ---------------------------------------------------------------------------
__global__ __launch_bounds__(256) void k_main(
    const float* __restrict__ vfeat, const float* __restrict__ vcoord,
    const float* __restrict__ n1g, const float* __restrict__ n1b,
    const float* __restrict__ kpw, const float* __restrict__ kpb,
    const float* __restrict__ in_w, const float* __restrict__ in_b,
    const float* __restrict__ ow, const float* __restrict__ l1w,
    const float* __restrict__ l2w, const float* __restrict__ fw,
    const float* __restrict__ qcoord,
    const float* __restrict__ qpw, const float* __restrict__ qpb,
    unsigned short* __restrict__ KVh, __hip_bfloat16* __restrict__ Eb,
    float* __restrict__ qout) {
  // One shared pool, aliased per branch (keeps LDS_Block_Size = 50176).
  __shared__ __align__(16) char smem[16384 + 64*264*2];
  const int b = blockIdx.x;
  const int t = threadIdx.x;
  if (b < NKV) {
    unsigned short* Gs  = reinterpret_cast<unsigned short*>(smem);          // [64][128] swizzled
    unsigned short* stg = reinterpret_cast<unsigned short*>(smem + 16384);  // [64][264]
    const int v0 = b * 64;
    // ---- Phase 1: LN + relu(key-pos), once per voxel ----
    {
      const int row = t >> 2;          // 0..63 (voxel within tile)
      const int q   = t & 3;           // channel quarter [q*32, q*32+32)
      const int j   = v0 + row;
      const float* vrow = vfeat + (size_t)j * CH + q*32;
      float4 xv[8];
      #pragma unroll
      for (int i = 0; i < 8; i++) xv[i] = reinterpret_cast<const float4*>(vrow)[i];
      float s = 0.0f, ss = 0.0f;
      #pragma unroll
      for (int i = 0; i < 8; i++) {
        s  += xv[i].x + xv[i].y + xv[i].z + xv[i].w;
        ss += xv[i].x*xv[i].x + xv[i].y*xv[i].y + xv[i].z*xv[i].z + xv[i].w*xv[i].w;
      }
      s += __shfl_xor(s, 1);  ss += __shfl_xor(ss, 1);
      s += __shfl_xor(s, 2);  ss += __shfl_xor(ss, 2);
      const float mean = s * (1.0f/CH);
      const float var  = ss * (1.0f/CH) - mean*mean;
      const float rstd = 1.0f / sqrtf(var + 1e-5f);
      const float c0 = vcoord[j*3+0], c1 = vcoord[j*3+1], c2 = vcoord[j*3+2];
      #pragma unroll
      for (int i = 0; i < 8; i++) {
        const int ch0 = q*32 + i*4;
        const float4 g4 = *reinterpret_cast<const float4*>(n1g + ch0);
        const float4 b4 = *reinterpret_cast<const float4*>(n1b + ch0);
        const float4 p4 = *reinterpret_cast<const float4*>(kpb + ch0);
        const float4 k0 = *reinterpret_cast<const float4*>(kpw + ch0*3);
        const float4 k1 = *reinterpret_cast<const float4*>(kpw + ch0*3 + 4);
        const float4 k2 = *reinterpret_cast<const float4*>(kpw + ch0*3 + 8);
        float o0 = fmaf((xv[i].x - mean)*rstd, g4.x, b4.x)
                 + fmaxf(fmaf(c0,k0.x, fmaf(c1,k0.y, fmaf(c2,k0.z, p4.x))), 0.0f);
        float o1 = fmaf((xv[i].y - mean)*rstd, g4.y, b4.y)
                 + fmaxf(fmaf(c0,k0.w, fmaf(c1,k1.x, fmaf(c2,k1.y, p4.y))), 0.0f);
        float o2 = fmaf((xv[i].z - mean)*rstd, g4.z, b4.z)
                 + fmaxf(fmaf(c0,k1.z, fmaf(c1,k1.w, fmaf(c2,k2.x, p4.z))), 0.0f);
        float o3 = fmaf((xv[i].w - mean)*rstd, g4.w, b4.w)
                 + fmaxf(fmaf(c0,k2.y, fmaf(c1,k2.z, fmaf(c2,k2.w, p4.w))), 0.0f);
        // Swizzled store: 16B unit index = ch0/8, XOR'd with (row&15).
        const int unit = (q*4 + (i >> 1)) ^ (row & 15);
        unsigned short* dst = Gs + row*128 + unit*8 + (i & 1)*4;
        *reinterpret_cast<uint2*>(dst) = make_uint2(pack2(o0,o1), pack2(o2,o3));
      }
    }
    __syncthreads();
    // ---- Phase 2: KV GEMM. Warp w handles heads 2w, 2w+1 (K and V each). ----
    {
      const int w    = t >> 6;
      const int lane = t & 63;
      const int col  = lane & 15;
      const int quad = lane >> 4;
      // B fragments (bf16 inline from f32): n = {K h0, V h0, K h1, V h1}.
      short8 bfr[4][4];
      float  bias[4];
      #pragma unroll
      for (int n = 0; n < 4; n++) {
        const int h    = 2*w + (n >> 1);
        const int base = ((n & 1) ? 2*CH : CH) + h*16;
        bias[n] = in_b[base + col];
        const float* wr = in_w + (size_t)(base + col)*CH + quad*8;
        #pragma unroll
        for (int kq = 0; kq < 4; kq++) {
          const float4 a = reinterpret_cast<const float4*>(wr + kq*32)[0];
          const float4 c = reinterpret_cast<const float4*>(wr + kq*32)[1];
          short8 bb;
          bb[0]=(short)f2bf(a.x); bb[1]=(short)f2bf(a.y);
          bb[2]=(short)f2bf(a.z); bb[3]=(short)f2bf(a.w);
          bb[4]=(short)f2bf(c.x); bb[5]=(short)f2bf(c.y);
          bb[6]=(short)f2bf(c.z); bb[7]=(short)f2bf(c.w);
          bfr[n][kq] = bb;
        }
      }
      #pragma unroll
      for (int m = 0; m < 4; m++) {
        short8 af[4];
        #pragma unroll
        for (int kq = 0; kq < 4; kq++) {
          const int unit = (kq*4 + quad) ^ col;   // (row&15)==col for row=m*16+col
          af[kq] = *reinterpret_cast<const short8*>(Gs + (m*16 + col)*128 + unit*8);
        }
        #pragma unroll
        for (int n = 0; n < 4; n++) {
          float4v acc = (float4v){bias[n], bias[n], bias[n], bias[n]};
          #pragma unroll
          for (int kq = 0; kq < 4; kq++)
            acc = __builtin_amdgcn_mfma_f32_16x16x32_bf16(af[kq], bfr[n][kq], acc, 0, 0, 0);
          const int h   = 2*w + (n >> 1);
          const int off = h*32 + (n & 1)*16 + col;
          #pragma unroll
          for (int r = 0; r < 4; r++)
            stg[(m*16 + quad*4 + r)*264 + off] = f2bf(acc[r]);
        }
      }
    }
    __syncthreads();
    // ---- Phase 3: coalesced copy to KVh (head-major, line = 16K|16V bf16) ----
    {
      const int h  = t >> 5;
      const int s5 = t & 31;
      #pragma unroll
      for (int vv = 0; vv < 2; vv++) {
        const int vox = s5*2 + vv;
        const uint4* src = reinterpret_cast<const uint4*>(stg + vox*264 + h*32);
        uint4* dst = reinterpret_cast<uint4*>(KVh + ((size_t)h*NVOX + v0 + vox)*32);
        #pragma unroll
        for (int u = 0; u < 4; u++) dst[u] = src[u];
      }
    }
  } else if (b < NKV + NEB) {
    // epilogue weights -> bf16
    const int idx = b - NKV;
    const int f = (idx * 256 + t) * 16;   // 0..98303
    const float* src;
    __hip_bfloat16* dst = Eb + f;
    if      (f < 16384) src = ow  + f;
    else if (f < 49152) src = l1w + (f - 16384);
    else if (f < 81920) src = l2w + (f - 49152);
    else                src = fw  + (f - 81920);
    float v[16];
    #pragma unroll
    for (int u = 0; u < 4; u++) {
      const float4 fq = *reinterpret_cast<const float4*>(src + u*4);
      v[u*4+0]=fq.x; v[u*4+1]=fq.y; v[u*4+2]=fq.z; v[u*4+3]=fq.w;
    }
    uint4* o = reinterpret_cast<uint4*>(dst);
    o[0] = make_uint4(pack2(v[0],v[1]), pack2(v[2],v[3]),
                      pack2(v[4],v[5]), pack2(v[6],v[7]));
    o[1] = make_uint4(pack2(v[8],v[9]), pack2(v[10],v[11]),
                      pack2(v[12],v[13]), pack2(v[14],v[15]));
  } else {
    // q projection: 16 queries per block.
    float (*qf)[CH] = reinterpret_cast<float (*)[CH]>(smem);
    const int qbase = (b - (NKV + NEB)) * 16;
    #pragma unroll
    for (int i = 0; i < 8; i++) {
      const int e = t + 256*i;
      const int qv = e >> 7, c = e & 127;
      const int qq = qbase + qv;
      const float v = fmaf(qcoord[qq*3+0], qpw[c*3+0],
                      fmaf(qcoord[qq*3+1], qpw[c*3+1],
                      fmaf(qcoord[qq*3+2], qpw[c*3+2], qpb[c])));
      qf[qv][c] = fmaxf(v, 0.0f);
    }
    __syncthreads();
    const int oc = t & 127, half = t >> 7;
    const float* wrow = in_w + (size_t)oc * CH;
    const float bia = in_b[oc];
    float acc[8];
    #pragma unroll
    for (int v = 0; v < 8; v++) acc[v] = bia;
    for (int c = 0; c < CH; c += 4) {
      const float4 w4 = *reinterpret_cast<const float4*>(wrow + c);
      #pragma unroll
      for (int v = 0; v < 8; v++) {
        const float4 g4 = *reinterpret_cast<const float4*>(&qf[half*8+v][c]);
        acc[v] = fmaf(g4.x, w4.x, fmaf(g4.y, w4.y, fmaf(g4.z, w4.z, fmaf(g4.w, w4.w, acc[v]))));
      }
    }
    #pragma unroll
    for (int v = 0; v < 8; v++) qout[(size_t)(qbase + half*8 + v)*CH + oc] = acc[v];
  }
}

// ---------------------------------------------------------------------------
// Kernel 3: attention with FUSED L2 warm prologue (unchanged). Block = (8q,1h);
// blockIdx.x = qg*8 + h (head<->XCD pinning).
// ---------------------------------------------------------------------------
__global__ __launch_bounds__(256) void k_attn(
    const unsigned short* __restrict__ KVh,
    const float* __restrict__ qg, const int* __restrict__ kidx,
    float* __restrict__ ctxg, unsigned* __restrict__ sink) {
  __shared__ float qs[8][16];
  __shared__ float sc[8*104];     // stride 104: conflict-free softmax/ctx reads
  __shared__ float red[128][9];   // slot-padded ctx partials
  __shared__ float rden[8];
  const int t    = threadIdx.x;
  const int h    = blockIdx.x & 7;
  const int n0   = (blockIdx.x >> 3) * 8;
  const int w    = t >> 6;
  const int lane = t & 63;
  const int quad = lane >> 2;     // 0..15
  const int r    = lane & 3;      // lane role within quad
  const int qh   = quad >> 3;     // 0/1: which of the wave's 2 queries
  const int g    = quad & 7;      // key slot group: keys g, g+8, ..., g+88
  const int q_l  = 2*w + qh;      // block-local query 0..7
  const unsigned short* KVbase = KVh + (size_t)h * NVOX * 32;

  // Fused warm: stream 40 sequential lines of this head's slice (overlapped).
  uint4 wv = make_uint4(0u, 0u, 0u, 0u);
  if (t < 40) {
    int line = (blockIdx.x >> 3) * 39 + t;
    if (line > NVOX - 1) line = NVOX - 1;
    wv = *reinterpret_cast<const uint4*>(KVbase + (size_t)line * 32);
  }

  if (t < 128) {
    const int q = t >> 4, d = t & 15;
    qs[q][d] = qg[(size_t)(n0 + q)*CH + h*16 + d];
  }
  // Loads: 12 keys per quad; each lane fetches its 16-B quarter of the line.
  unsigned msk = 0;
  uint4 kvbuf[12];
  const int krow = (n0 + q_l)*KK + g;
  #pragma unroll
  for (int it = 0; it < 12; it++) {
    const int j0 = kidx[krow + it*8];
    msk |= (unsigned)(j0 < 0) << it;
    const int j = (j0 < 0) ? 0 : j0;   // clamp like reference
    kvbuf[it] = *reinterpret_cast<const uint4*>(KVbase + (size_t)j*32 + r*8);
  }
  __syncthreads();
  // Scores: r0/r1 lanes hold K halves; q half selected by r&1.
  const float4 qa = *reinterpret_cast<const float4*>(&qs[q_l][(r & 1)*8]);
  const float4 qb = *reinterpret_cast<const float4*>(&qs[q_l][(r & 1)*8 + 4]);
  #pragma unroll
  for (int it = 0; it < 12; it++) {
    const uint4 kv = kvbuf[it];
    float s = 0.0f;
    s = fmaf(qa.x, bflo(kv.x), s); s = fmaf(qa.y, bfhi(kv.x), s);
    s = fmaf(qa.z, bflo(kv.y), s); s = fmaf(qa.w, bfhi(kv.y), s);
    s = fmaf(qb.x, bflo(kv.z), s); s = fmaf(qb.y, bfhi(kv.z), s);
    s = fmaf(qb.z, bflo(kv.w), s); s = fmaf(qb.w, bfhi(kv.w), s);
    s += __shfl_xor(s, 1);          // r0+r1 (K full dot); r2+r3 garbage unused
    if (r == 0)
      sc[q_l*104 + g + it*8] = ((msk >> it) & 1) ? -1e9f : s * 0.25f;
  }
  __syncthreads();
  // Softmax per query: 16 lanes over 96 keys.
  if (t < 128) {
    const int q = t >> 4, l = t & 15;
    float mx = -3e38f;
    #pragma unroll
    for (int k = l; k < KK; k += 16) mx = fmaxf(mx, sc[q*104 + k]);
    #pragma unroll
    for (int m = 8; m >= 1; m >>= 1) mx = fmaxf(mx, __shfl_xor(mx, m));
    float sum = 0.0f;
    #pragma unroll
    for (int k = l; k < KK; k += 16) {
      const float p = __expf(sc[q*104 + k] - mx);   // masked -> exactly 0
      sc[q*104 + k] = p;
      sum += p;
    }
    #pragma unroll
    for (int m = 8; m >= 1; m >>= 1) sum += __shfl_xor(sum, m);
    if (l == 0) rden[q] = 1.0f / sum;
  }
  __syncthreads();
  // ctx: r2/r3 lanes accumulate their V half over their 12 keys.
  {
    float acc[8] = {0,0,0,0,0,0,0,0};
    #pragma unroll
    for (int it = 0; it < 12; it++) {
      const float wg = sc[q_l*104 + g + it*8];   // broadcast within quad
      const uint4 kv = kvbuf[it];
      acc[0] = fmaf(wg, bflo(kv.x), acc[0]); acc[1] = fmaf(wg, bfhi(kv.x), acc[1]);
      acc[2] = fmaf(wg, bflo(kv.y), acc[2]); acc[3] = fmaf(wg, bfhi(kv.y), acc[3]);
      acc[4] = fmaf(wg, bflo(kv.z), acc[4]); acc[5] = fmaf(wg, bfhi(kv.z), acc[5]);
      acc[6] = fmaf(wg, bflo(kv.w), acc[6]); acc[7] = fmaf(wg, bfhi(kv.w), acc[7]);
    }
    if (r >= 2) {
      const int slot = q_l*16 + g*2 + (r - 2);   // 0..127
      #pragma unroll
      for (int u = 0; u < 8; u++) red[slot][u] = acc[u];
    }
  }
  __syncthreads();
  // Reduce 8 slot-groups per (query, channel) and store.
  if (t < 128) {
    const int q = t >> 4, d = t & 15;
    const int half = d >> 3, u = d & 7;
    float s = 0.0f;
    #pragma unroll
    for (int gg = 0; gg < 8; gg++) s += red[q*16 + gg*2 + half][u];
    ctxg[(size_t)(n0 + q)*CH + h*16 + d] = s * rden[q];
  }
  // Warm-load consumption (impossible condition; waitcnt lands here, after
  // all useful work, so the warm never stalls the block).
  const unsigned accw = wv.x ^ wv.y ^ wv.z ^ wv.w;
  if (accw == 0x9E3779B9u && t == 255) sink[0] = accw;
}

// ---------------------------------------------------------------------------
// Kernel 4: epilogue via MFMA bf16 (unchanged).
// ---------------------------------------------------------------------------
__global__ __launch_bounds__(256) void k_epi(
    const float* __restrict__ ctxg, const __hip_bfloat16* __restrict__ Eb,
    const float* __restrict__ ob,
    const float* __restrict__ n2g, const float* __restrict__ n2b,
    const float* __restrict__ l1b, const float* __restrict__ l2b,
    const float* __restrict__ fb,
    float* __restrict__ outp) {
  __shared__ unsigned short csb[16][136];
  __shared__ float attnS[16][132];
  __shared__ unsigned short hb[16][136];
  __shared__ unsigned short a1b[16][264];
  __shared__ unsigned short xb[16][136];
  const unsigned short* owb  = reinterpret_cast<const unsigned short*>(Eb);
  const unsigned short* l1wb = owb + 16384;
  const unsigned short* l2wb = owb + 49152;
  const unsigned short* fwb  = owb + 81920;

  const int t = threadIdx.x;
  const int w = t >> 6;
  const int lane = t & 63;
  const int col = lane & 15;
  const int quad = lane >> 4;
  const int qbase = blockIdx.x * 16;

  {
    const int e = t * 8;
    const int row = e >> 7, cc = e & 127;
    const float4* src = reinterpret_cast<const float4*>(ctxg + (size_t)(qbase+row)*CH + cc);
    const float4 x0 = src[0], x1 = src[1];
    *reinterpret_cast<uint4*>(&csb[row][cc]) =
        make_uint4(pack2(x0.x,x0.y), pack2(x0.z,x0.w), pack2(x1.x,x1.y), pack2(x1.z,x1.w));
  }
  __syncthreads();
  {
    short8 af[4];
    #pragma unroll
    for (int kq = 0; kq < 4; kq++)
      af[kq] = *reinterpret_cast<const short8*>(&csb[col][quad*8 + kq*32]);
    #pragma unroll
    for (int j = 0; j < 2; j++) {
      const int n0 = w*32 + j*16;
      const float bia = ob[n0 + col];
      float4v acc = (float4v){bia, bia, bia, bia};
      #pragma unroll
      for (int kq = 0; kq < 4; kq++) {
        const short8 bf = *reinterpret_cast<const short8*>(
            owb + (size_t)(n0 + col)*CH + kq*32 + quad*8);
        acc = __builtin_amdgcn_mfma_f32_16x16x32_bf16(af[kq], bf, acc, 0, 0, 0);
      }
      #pragma unroll
      for (int r = 0; r < 4; r++) attnS[quad*4 + r][n0 + col] = acc[r];
    }
  }
  __syncthreads();
  {
    const int row = t >> 4, l = t & 15;
    float s = 0.0f, ss = 0.0f;
    #pragma unroll
    for (int c = l; c < CH; c += 16) { const float x = attnS[row][c]; s += x; ss += x*x; }
    #pragma unroll
    for (int m = 8; m >= 1; m >>= 1) { s += __shfl_xor(s, m); ss += __shfl_xor(ss, m); }
    const float mean = s * (1.0f/CH);
    const float var  = ss * (1.0f/CH) - mean*mean;
    const float rstd = 1.0f / sqrtf(var + 1e-5f);
    #pragma unroll
    for (int c = l; c < CH; c += 16)
      hb[row][c] = f2bf((attnS[row][c] - mean) * rstd * n2g[c] + n2b[c]);
  }
  __syncthreads();
  {
    short8 af[4];
    #pragma unroll
    for (int kq = 0; kq < 4; kq++)
      af[kq] = *reinterpret_cast<const short8*>(&hb[col][quad*8 + kq*32]);
    #pragma unroll
    for (int j = 0; j < 4; j++) {
      const int n0 = w*64 + j*16;
      const float bia = l1b[n0 + col];
      float4v acc = (float4v){bia, bia, bia, bia};
      #pragma unroll
      for (int kq = 0; kq < 4; kq++) {
        const short8 bf = *reinterpret_cast<const short8*>(
            l1wb + (size_t)(n0 + col)*CH + kq*32 + quad*8);
        acc = __builtin_amdgcn_mfma_f32_16x16x32_bf16(af[kq], bf, acc, 0, 0, 0);
      }
      #pragma unroll
      for (int r = 0; r < 4; r++)
        a1b[quad*4 + r][n0 + col] = f2bf(fmaxf(acc[r], 0.0f));
    }
  }
  __syncthreads();
  {
    short8 af[8];
    #pragma unroll
    for (int kq = 0; kq < 8; kq++)
      af[kq] = *reinterpret_cast<const short8*>(&a1b[col][quad*8 + kq*32]);
    #pragma unroll
    for (int j = 0; j < 2; j++) {
      const int n0 = w*32 + j*16;
      const float bia = l2b[n0 + col];
      float4v acc = (float4v){bia, bia, bia, bia};
      #pragma unroll
      for (int kq = 0; kq < 8; kq++) {
        const short8 bf = *reinterpret_cast<const short8*>(
            l2wb + (size_t)(n0 + col)*FFD + kq*32 + quad*8);
        acc = __builtin_amdgcn_mfma_f32_16x16x32_bf16(af[kq], bf, acc, 0, 0, 0);
      }
      #pragma unroll
      for (int r = 0; r < 4; r++)
        xb[quad*4 + r][n0 + col] = f2bf(acc[r] + attnS[quad*4 + r][n0 + col]);
    }
  }
  __syncthreads();
  {
    short8 af[4];
    #pragma unroll
    for (int kq = 0; kq < 4; kq++)
      af[kq] = *reinterpret_cast<const short8*>(&xb[col][quad*8 + kq*32]);
    #pragma unroll
    for (int j = 0; j < 2; j++) {
      const int n0 = w*32 + j*16;
      const float bia = fb[n0 + col];
      float4v acc = (float4v){bia, bia, bia, bia};
      #pragma unroll
      for (int kq = 0; kq < 4; kq++) {
        const short8 bf = *reinterpret_cast<const short8*>(
            fwb + (size_t)(n0 + col)*CH + kq*32 + quad*8);
        acc = __builtin_amdgcn_mfma_f32_16x16x32_bf16(af[kq], bf, acc, 0, 0, 0);
      }
      #pragma unroll
      for (int r = 0; r < 4; r++)
        outp[(size_t)(qbase + quad*4 + r)*CH + n0 + col] = fmaxf(acc[r], 0.0f);
    }
  }
}

// ---------------------------------------------------------------------------
extern "C" void kernel_launch(void* const* d_in, const int* in_sizes, int n_in,
                              void* d_out, int out_size, void* d_ws, size_t ws_size,
                              hipStream_t stream) {
  const float* vfeat  = (const float*)d_in[0];
  const float* vcoord = (const float*)d_in[1];
  const float* qcoord = (const float*)d_in[2];
  const int*   kidx   = (const int*)  d_in[3];
  const float* n1g    = (const float*)d_in[4];
  const float* n1b    = (const float*)d_in[5];
  const float* qpw    = (const float*)d_in[6];
  const float* qpb    = (const float*)d_in[7];
  const float* kpw    = (const float*)d_in[8];
  const float* kpb    = (const float*)d_in[9];
  const float* in_w   = (const float*)d_in[10];
  const float* in_b   = (const float*)d_in[11];
  const float* out_w  = (const float*)d_in[12];
  const float* out_b  = (const float*)d_in[13];
  const float* n2g    = (const float*)d_in[14];
  const float* n2b    = (const float*)d_in[15];
  const float* l1w    = (const float*)d_in[16];
  const float* l1b    = (const float*)d_in[17];
  const float* l2w    = (const float*)d_in[18];
  const float* l2b    = (const float*)d_in[19];
  const float* fw     = (const float*)d_in[20];
  const float* fb     = (const float*)d_in[21];
  float* out = (float*)d_out;

  unsigned short* KVh = (unsigned short*)d_ws;               // 8*NVOX*32 shorts (20.5 MB)
  __hip_bfloat16* Eb = (__hip_bfloat16*)(KVh + (size_t)8*NVOX*32);  // 98304 bf16 epi weights
  float* qb = (float*)(Eb + 98304);                          // NQRY*CH f32
  float* cx = qb + (size_t)NQRY*CH;                          // NQRY*CH f32
  unsigned* sink = (unsigned*)(cx + (size_t)NQRY*CH);        // 1 dword DCE guard

  k_main<<<NKV + NEB + NQRY/16, 256, 0, stream>>>(
      vfeat, vcoord, n1g, n1b, kpw, kpb, in_w, in_b,
      out_w, l1w, l2w, fw, qcoord, qpw, qpb, KVh, Eb, qb);
  k_attn<<<(NQRY/8)*8, 256, 0, stream>>>(KVh, qb, kidx, cx, sink);
  k_epi <<<NQRY/16, 256, 0, stream>>>(cx, Eb, out_b, n2g, n2b, l1b, l2b, fb, out);
}

// Round 3
// 196.390 us; speedup vs baseline: 1.2680x; 1.0149x over previous
//
#include <hip/hip_runtime.h>
#include <hip/hip_bf16.h>
#include <math.h>

// Problem constants (fixed by reference).
constexpr int NVOX = 40000;
constexpr int NQRY = 8192;
constexpr int KK   = 96;
constexpr int CH   = 128;
constexpr int FFD  = 256;
constexpr int VT   = 32;               // voxels per KV block
constexpr int NKV  = NVOX / VT;        // 1250 fused LN+KV blocks (all 8 heads each)
constexpr int NEB  = 24;               // epilogue-weight convert blocks

typedef __attribute__((ext_vector_type(8))) short short8;
typedef __attribute__((ext_vector_type(4))) float float4v;

__device__ inline float bflo(unsigned u) { return __uint_as_float(u << 16); }
__device__ inline float bfhi(unsigned u) { return __uint_as_float(u & 0xffff0000u); }
__device__ inline unsigned short f2bf(float x) {
  union { float f; unsigned u; } a; a.f = x;
  const unsigned r = a.u + 0x7fffu + ((a.u >> 16) & 1u);  // round-to-nearest-even
  return (unsigned short)(r >> 16);
}
__device__ inline unsigned pack2(float lo, float hi) {
  return (unsigned)f2bf(lo) | ((unsigned)f2bf(hi) << 16);
}

// ---------------------------------------------------------------------------
// Kernel 1 (fused, redundancy-free, occupancy-tuned):
//  blocks [0, NKV):        32 voxels: LN+relu(key-pos) ONCE -> swizzled LDS
//                          tile; then 4 warps x 2 heads: KV GEMM via MFMA with
//                          B-frags converted inline from f32 in_w. -> KVh.
//  blocks [NKV, NKV+24):   epilogue weights -> Eb bf16
//  blocks [NKV+24, +512):  q = relu(qc@q_pos_w.T+b) @ wq.T + bq -> qb f32
// LDS = 8192 (Gs) + 16896 (stg) = 25088 B -> up to 6 blocks/CU by LDS.
// ---------------------------------------------------------------------------
__global__ __launch_bounds__(256) void k_main(
    const float* __restrict__ vfeat, const float* __restrict__ vcoord,
    const float* __restrict__ n1g, const float* __restrict__ n1b,
    const float* __restrict__ kpw, const float* __restrict__ kpb,
    const float* __restrict__ in_w, const float* __restrict__ in_b,
    const float* __restrict__ ow, const float* __restrict__ l1w,
    const float* __restrict__ l2w, const float* __restrict__ fw,
    const float* __restrict__ qcoord,
    const float* __restrict__ qpw, const float* __restrict__ qpb,
    unsigned short* __restrict__ KVh, __hip_bfloat16* __restrict__ Eb,
    float* __restrict__ qout) {
  __shared__ __align__(16) char smem[VT*128*2 + VT*264*2];   // 25088 B
  const int b = blockIdx.x;
  const int t = threadIdx.x;
  if (b < NKV) {
    unsigned short* Gs  = reinterpret_cast<unsigned short*>(smem);            // [32][128] swizzled bf16
    unsigned short* stg = reinterpret_cast<unsigned short*>(smem + VT*128*2); // [32][264]
    const int v0 = b * VT;
    // ---- Phase 1: LN + relu(key-pos), once per voxel (8 lanes/voxel) ----
    {
      const int row = t >> 3;          // 0..31 voxel within tile
      const int q   = t & 7;           // 16-channel group [q*16, q*16+16)
      const int j   = v0 + row;
      const float* vrow = vfeat + (size_t)j * CH + q*16;
      float4 xv[4];
      #pragma unroll
      for (int i = 0; i < 4; i++) xv[i] = reinterpret_cast<const float4*>(vrow)[i];
      float s = 0.0f, ss = 0.0f;
      #pragma unroll
      for (int i = 0; i < 4; i++) {
        s  += xv[i].x + xv[i].y + xv[i].z + xv[i].w;
        ss += xv[i].x*xv[i].x + xv[i].y*xv[i].y + xv[i].z*xv[i].z + xv[i].w*xv[i].w;
      }
      s += __shfl_xor(s, 1);  ss += __shfl_xor(ss, 1);
      s += __shfl_xor(s, 2);  ss += __shfl_xor(ss, 2);
      s += __shfl_xor(s, 4);  ss += __shfl_xor(ss, 4);
      const float mean = s * (1.0f/CH);
      const float var  = ss * (1.0f/CH) - mean*mean;
      const float rstd = 1.0f / sqrtf(var + 1e-5f);
      const float c0 = vcoord[j*3+0], c1 = vcoord[j*3+1], c2 = vcoord[j*3+2];
      #pragma unroll
      for (int i = 0; i < 4; i++) {
        const int ch0 = q*16 + i*4;
        const float4 g4 = *reinterpret_cast<const float4*>(n1g + ch0);
        const float4 b4 = *reinterpret_cast<const float4*>(n1b + ch0);
        const float4 p4 = *reinterpret_cast<const float4*>(kpb + ch0);
        const float4 k0 = *reinterpret_cast<const float4*>(kpw + ch0*3);
        const float4 k1 = *reinterpret_cast<const float4*>(kpw + ch0*3 + 4);
        const float4 k2 = *reinterpret_cast<const float4*>(kpw + ch0*3 + 8);
        float o0 = fmaf((xv[i].x - mean)*rstd, g4.x, b4.x)
                 + fmaxf(fmaf(c0,k0.x, fmaf(c1,k0.y, fmaf(c2,k0.z, p4.x))), 0.0f);
        float o1 = fmaf((xv[i].y - mean)*rstd, g4.y, b4.y)
                 + fmaxf(fmaf(c0,k0.w, fmaf(c1,k1.x, fmaf(c2,k1.y, p4.y))), 0.0f);
        float o2 = fmaf((xv[i].z - mean)*rstd, g4.z, b4.z)
                 + fmaxf(fmaf(c0,k1.z, fmaf(c1,k1.w, fmaf(c2,k2.x, p4.z))), 0.0f);
        float o3 = fmaf((xv[i].w - mean)*rstd, g4.w, b4.w)
                 + fmaxf(fmaf(c0,k2.y, fmaf(c1,k2.z, fmaf(c2,k2.w, p4.w))), 0.0f);
        // Swizzled store: 16B unit = ch0/8, XOR'd with (row&15); half = i&1.
        const int unit = (2*q + (i >> 1)) ^ (row & 15);
        unsigned short* dst = Gs + row*128 + unit*8 + (i & 1)*4;
        *reinterpret_cast<uint2*>(dst) = make_uint2(pack2(o0,o1), pack2(o2,o3));
      }
    }
    __syncthreads();
    // ---- Phase 2: KV GEMM. Warp w handles heads 2w, 2w+1 (K and V each). ----
    {
      const int w    = t >> 6;
      const int lane = t & 63;
      const int col  = lane & 15;
      const int quad = lane >> 4;
      // B fragments (bf16 inline from f32): n = {K h0, V h0, K h1, V h1}.
      short8 bfr[4][4];
      float  bias[4];
      #pragma unroll
      for (int n = 0; n < 4; n++) {
        const int h    = 2*w + (n >> 1);
        const int base = ((n & 1) ? 2*CH : CH) + h*16;
        bias[n] = in_b[base + col];
        const float* wr = in_w + (size_t)(base + col)*CH + quad*8;
        #pragma unroll
        for (int kq = 0; kq < 4; kq++) {
          const float4 a = reinterpret_cast<const float4*>(wr + kq*32)[0];
          const float4 c = reinterpret_cast<const float4*>(wr + kq*32)[1];
          short8 bb;
          bb[0]=(short)f2bf(a.x); bb[1]=(short)f2bf(a.y);
          bb[2]=(short)f2bf(a.z); bb[3]=(short)f2bf(a.w);
          bb[4]=(short)f2bf(c.x); bb[5]=(short)f2bf(c.y);
          bb[6]=(short)f2bf(c.z); bb[7]=(short)f2bf(c.w);
          bfr[n][kq] = bb;
        }
      }
      #pragma unroll
      for (int m = 0; m < 2; m++) {
        short8 af[4];
        #pragma unroll
        for (int kq = 0; kq < 4; kq++) {
          const int unit = (kq*4 + quad) ^ col;   // (row&15)==col for row=m*16+col
          af[kq] = *reinterpret_cast<const short8*>(Gs + (m*16 + col)*128 + unit*8);
        }
        #pragma unroll
        for (int n = 0; n < 4; n++) {
          float4v acc = (float4v){bias[n], bias[n], bias[n], bias[n]};
          #pragma unroll
          for (int kq = 0; kq < 4; kq++)
            acc = __builtin_amdgcn_mfma_f32_16x16x32_bf16(af[kq], bfr[n][kq], acc, 0, 0, 0);
          const int h   = 2*w + (n >> 1);
          const int off = h*32 + (n & 1)*16 + col;
          #pragma unroll
          for (int r = 0; r < 4; r++)
            stg[(m*16 + quad*4 + r)*264 + off] = f2bf(acc[r]);
        }
      }
    }
    __syncthreads();
    // ---- Phase 3: coalesced copy to KVh (head-major, line = 16K|16V bf16) ----
    {
      const int h   = t >> 5;
      const int vox = t & 31;
      const uint4* src = reinterpret_cast<const uint4*>(stg + vox*264 + h*32);
      uint4* dst = reinterpret_cast<uint4*>(KVh + ((size_t)h*NVOX + v0 + vox)*32);
      #pragma unroll
      for (int u = 0; u < 4; u++) dst[u] = src[u];
    }
  } else if (b < NKV + NEB) {
    // epilogue weights -> bf16
    const int idx = b - NKV;
    const int f = (idx * 256 + t) * 16;   // 0..98303
    const float* src;
    __hip_bfloat16* dst = Eb + f;
    if      (f < 16384) src = ow  + f;
    else if (f < 49152) src = l1w + (f - 16384);
    else if (f < 81920) src = l2w + (f - 49152);
    else                src = fw  + (f - 81920);
    float v[16];
    #pragma unroll
    for (int u = 0; u < 4; u++) {
      const float4 fq = *reinterpret_cast<const float4*>(src + u*4);
      v[u*4+0]=fq.x; v[u*4+1]=fq.y; v[u*4+2]=fq.z; v[u*4+3]=fq.w;
    }
    uint4* o = reinterpret_cast<uint4*>(dst);
    o[0] = make_uint4(pack2(v[0],v[1]), pack2(v[2],v[3]),
                      pack2(v[4],v[5]), pack2(v[6],v[7]));
    o[1] = make_uint4(pack2(v[8],v[9]), pack2(v[10],v[11]),
                      pack2(v[12],v[13]), pack2(v[14],v[15]));
  } else {
    // q projection: 16 queries per block.
    float (*qf)[CH] = reinterpret_cast<float (*)[CH]>(smem);
    const int qbase = (b - (NKV + NEB)) * 16;
    #pragma unroll
    for (int i = 0; i < 8; i++) {
      const int e = t + 256*i;
      const int qv = e >> 7, c = e & 127;
      const int qq = qbase + qv;
      const float v = fmaf(qcoord[qq*3+0], qpw[c*3+0],
                      fmaf(qcoord[qq*3+1], qpw[c*3+1],
                      fmaf(qcoord[qq*3+2], qpw[c*3+2], qpb[c])));
      qf[qv][c] = fmaxf(v, 0.0f);
    }
    __syncthreads();
    const int oc = t & 127, half = t >> 7;
    const float* wrow = in_w + (size_t)oc * CH;
    const float bia = in_b[oc];
    float acc[8];
    #pragma unroll
    for (int v = 0; v < 8; v++) acc[v] = bia;
    for (int c = 0; c < CH; c += 4) {
      const float4 w4 = *reinterpret_cast<const float4*>(wrow + c);
      #pragma unroll
      for (int v = 0; v < 8; v++) {
        const float4 g4 = *reinterpret_cast<const float4*>(&qf[half*8+v][c]);
        acc[v] = fmaf(g4.x, w4.x, fmaf(g4.y, w4.y, fmaf(g4.z, w4.z, fmaf(g4.w, w4.w, acc[v]))));
      }
    }
    #pragma unroll
    for (int v = 0; v < 8; v++) qout[(size_t)(qbase + half*8 + v)*CH + oc] = acc[v];
  }
}

// ---------------------------------------------------------------------------
// Kernel 3: attention with FUSED L2 warm prologue (unchanged). Block = (8q,1h);
// blockIdx.x = qg*8 + h (head<->XCD pinning).
// ---------------------------------------------------------------------------
__global__ __launch_bounds__(256) void k_attn(
    const unsigned short* __restrict__ KVh,
    const float* __restrict__ qg, const int* __restrict__ kidx,
    float* __restrict__ ctxg, unsigned* __restrict__ sink) {
  __shared__ float qs[8][16];
  __shared__ float sc[8*104];     // stride 104: conflict-free softmax/ctx reads
  __shared__ float red[128][9];   // slot-padded ctx partials
  __shared__ float rden[8];
  const int t    = threadIdx.x;
  const int h    = blockIdx.x & 7;
  const int n0   = (blockIdx.x >> 3) * 8;
  const int w    = t >> 6;
  const int lane = t & 63;
  const int quad = lane >> 2;     // 0..15
  const int r    = lane & 3;      // lane role within quad
  const int qh   = quad >> 3;     // 0/1: which of the wave's 2 queries
  const int g    = quad & 7;      // key slot group: keys g, g+8, ..., g+88
  const int q_l  = 2*w + qh;      // block-local query 0..7
  const unsigned short* KVbase = KVh + (size_t)h * NVOX * 32;

  // Fused warm: stream 40 sequential lines of this head's slice (overlapped).
  uint4 wv = make_uint4(0u, 0u, 0u, 0u);
  if (t < 40) {
    int line = (blockIdx.x >> 3) * 39 + t;
    if (line > NVOX - 1) line = NVOX - 1;
    wv = *reinterpret_cast<const uint4*>(KVbase + (size_t)line * 32);
  }

  if (t < 128) {
    const int q = t >> 4, d = t & 15;
    qs[q][d] = qg[(size_t)(n0 + q)*CH + h*16 + d];
  }
  // Loads: 12 keys per quad; each lane fetches its 16-B quarter of the line.
  unsigned msk = 0;
  uint4 kvbuf[12];
  const int krow = (n0 + q_l)*KK + g;
  #pragma unroll
  for (int it = 0; it < 12; it++) {
    const int j0 = kidx[krow + it*8];
    msk |= (unsigned)(j0 < 0) << it;
    const int j = (j0 < 0) ? 0 : j0;   // clamp like reference
    kvbuf[it] = *reinterpret_cast<const uint4*>(KVbase + (size_t)j*32 + r*8);
  }
  __syncthreads();
  // Scores: r0/r1 lanes hold K halves; q half selected by r&1.
  const float4 qa = *reinterpret_cast<const float4*>(&qs[q_l][(r & 1)*8]);
  const float4 qb = *reinterpret_cast<const float4*>(&qs[q_l][(r & 1)*8 + 4]);
  #pragma unroll
  for (int it = 0; it < 12; it++) {
    const uint4 kv = kvbuf[it];
    float s = 0.0f;
    s = fmaf(qa.x, bflo(kv.x), s); s = fmaf(qa.y, bfhi(kv.x), s);
    s = fmaf(qa.z, bflo(kv.y), s); s = fmaf(qa.w, bfhi(kv.y), s);
    s = fmaf(qb.x, bflo(kv.z), s); s = fmaf(qb.y, bfhi(kv.z), s);
    s = fmaf(qb.z, bflo(kv.w), s); s = fmaf(qb.w, bfhi(kv.w), s);
    s += __shfl_xor(s, 1);          // r0+r1 (K full dot); r2+r3 garbage unused
    if (r == 0)
      sc[q_l*104 + g + it*8] = ((msk >> it) & 1) ? -1e9f : s * 0.25f;
  }
  __syncthreads();
  // Softmax per query: 16 lanes over 96 keys.
  if (t < 128) {
    const int q = t >> 4, l = t & 15;
    float mx = -3e38f;
    #pragma unroll
    for (int k = l; k < KK; k += 16) mx = fmaxf(mx, sc[q*104 + k]);
    #pragma unroll
    for (int m = 8; m >= 1; m >>= 1) mx = fmaxf(mx, __shfl_xor(mx, m));
    float sum = 0.0f;
    #pragma unroll
    for (int k = l; k < KK; k += 16) {
      const float p = __expf(sc[q*104 + k] - mx);   // masked -> exactly 0
      sc[q*104 + k] = p;
      sum += p;
    }
    #pragma unroll
    for (int m = 8; m >= 1; m >>= 1) sum += __shfl_xor(sum, m);
    if (l == 0) rden[q] = 1.0f / sum;
  }
  __syncthreads();
  // ctx: r2/r3 lanes accumulate their V half over their 12 keys.
  {
    float acc[8] = {0,0,0,0,0,0,0,0};
    #pragma unroll
    for (int it = 0; it < 12; it++) {
      const float wg = sc[q_l*104 + g + it*8];   // broadcast within quad
      const uint4 kv = kvbuf[it];
      acc[0] = fmaf(wg, bflo(kv.x), acc[0]); acc[1] = fmaf(wg, bfhi(kv.x), acc[1]);
      acc[2] = fmaf(wg, bflo(kv.y), acc[2]); acc[3] = fmaf(wg, bfhi(kv.y), acc[3]);
      acc[4] = fmaf(wg, bflo(kv.z), acc[4]); acc[5] = fmaf(wg, bfhi(kv.z), acc[5]);
      acc[6] = fmaf(wg, bflo(kv.w), acc[6]); acc[7] = fmaf(wg, bfhi(kv.w), acc[7]);
    }
    if (r >= 2) {
      const int slot = q_l*16 + g*2 + (r - 2);   // 0..127
      #pragma unroll
      for (int u = 0; u < 8; u++) red[slot][u] = acc[u];
    }
  }
  __syncthreads();
  // Reduce 8 slot-groups per (query, channel) and store.
  if (t < 128) {
    const int q = t >> 4, d = t & 15;
    const int half = d >> 3, u = d & 7;
    float s = 0.0f;
    #pragma unroll
    for (int gg = 0; gg < 8; gg++) s += red[q*16 + gg*2 + half][u];
    ctxg[(size_t)(n0 + q)*CH + h*16 + d] = s * rden[q];
  }
  // Warm-load consumption (impossible condition; waitcnt lands here, after
  // all useful work, so the warm never stalls the block).
  const unsigned accw = wv.x ^ wv.y ^ wv.z ^ wv.w;
  if (accw == 0x9E3779B9u && t == 255) sink[0] = accw;
}

// ---------------------------------------------------------------------------
// Kernel 4: epilogue via MFMA bf16 (unchanged).
// ---------------------------------------------------------------------------
__global__ __launch_bounds__(256) void k_epi(
    const float* __restrict__ ctxg, const __hip_bfloat16* __restrict__ Eb,
    const float* __restrict__ ob,
    const float* __restrict__ n2g, const float* __restrict__ n2b,
    const float* __restrict__ l1b, const float* __restrict__ l2b,
    const float* __restrict__ fb,
    float* __restrict__ outp) {
  __shared__ unsigned short csb[16][136];
  __shared__ float attnS[16][132];
  __shared__ unsigned short hb[16][136];
  __shared__ unsigned short a1b[16][264];
  __shared__ unsigned short xb[16][136];
  const unsigned short* owb  = reinterpret_cast<const unsigned short*>(Eb);
  const unsigned short* l1wb = owb + 16384;
  const unsigned short* l2wb = owb + 49152;
  const unsigned short* fwb  = owb + 81920;

  const int t = threadIdx.x;
  const int w = t >> 6;
  const int lane = t & 63;
  const int col = lane & 15;
  const int quad = lane >> 4;
  const int qbase = blockIdx.x * 16;

  {
    const int e = t * 8;
    const int row = e >> 7, cc = e & 127;
    const float4* src = reinterpret_cast<const float4*>(ctxg + (size_t)(qbase+row)*CH + cc);
    const float4 x0 = src[0], x1 = src[1];
    *reinterpret_cast<uint4*>(&csb[row][cc]) =
        make_uint4(pack2(x0.x,x0.y), pack2(x0.z,x0.w), pack2(x1.x,x1.y), pack2(x1.z,x1.w));
  }
  __syncthreads();
  {
    short8 af[4];
    #pragma unroll
    for (int kq = 0; kq < 4; kq++)
      af[kq] = *reinterpret_cast<const short8*>(&csb[col][quad*8 + kq*32]);
    #pragma unroll
    for (int j = 0; j < 2; j++) {
      const int n0 = w*32 + j*16;
      const float bia = ob[n0 + col];
      float4v acc = (float4v){bia, bia, bia, bia};
      #pragma unroll
      for (int kq = 0; kq < 4; kq++) {
        const short8 bf = *reinterpret_cast<const short8*>(
            owb + (size_t)(n0 + col)*CH + kq*32 + quad*8);
        acc = __builtin_amdgcn_mfma_f32_16x16x32_bf16(af[kq], bf, acc, 0, 0, 0);
      }
      #pragma unroll
      for (int r = 0; r < 4; r++) attnS[quad*4 + r][n0 + col] = acc[r];
    }
  }
  __syncthreads();
  {
    const int row = t >> 4, l = t & 15;
    float s = 0.0f, ss = 0.0f;
    #pragma unroll
    for (int c = l; c < CH; c += 16) { const float x = attnS[row][c]; s += x; ss += x*x; }
    #pragma unroll
    for (int m = 8; m >= 1; m >>= 1) { s += __shfl_xor(s, m); ss += __shfl_xor(ss, m); }
    const float mean = s * (1.0f/CH);
    const float var  = ss * (1.0f/CH) - mean*mean;
    const float rstd = 1.0f / sqrtf(var + 1e-5f);
    #pragma unroll
    for (int c = l; c < CH; c += 16)
      hb[row][c] = f2bf((attnS[row][c] - mean) * rstd * n2g[c] + n2b[c]);
  }
  __syncthreads();
  {
    short8 af[4];
    #pragma unroll
    for (int kq = 0; kq < 4; kq++)
      af[kq] = *reinterpret_cast<const short8*>(&hb[col][quad*8 + kq*32]);
    #pragma unroll
    for (int j = 0; j < 4; j++) {
      const int n0 = w*64 + j*16;
      const float bia = l1b[n0 + col];
      float4v acc = (float4v){bia, bia, bia, bia};
      #pragma unroll
      for (int kq = 0; kq < 4; kq++) {
        const short8 bf = *reinterpret_cast<const short8*>(
            l1wb + (size_t)(n0 + col)*CH + kq*32 + quad*8);
        acc = __builtin_amdgcn_mfma_f32_16x16x32_bf16(af[kq], bf, acc, 0, 0, 0);
      }
      #pragma unroll
      for (int r = 0; r < 4; r++)
        a1b[quad*4 + r][n0 + col] = f2bf(fmaxf(acc[r], 0.0f));
    }
  }
  __syncthreads();
  {
    short8 af[8];
    #pragma unroll
    for (int kq = 0; kq < 8; kq++)
      af[kq] = *reinterpret_cast<const short8*>(&a1b[col][quad*8 + kq*32]);
    #pragma unroll
    for (int j = 0; j < 2; j++) {
      const int n0 = w*32 + j*16;
      const float bia = l2b[n0 + col];
      float4v acc = (float4v){bia, bia, bia, bia};
      #pragma unroll
      for (int kq = 0; kq < 8; kq++) {
        const short8 bf = *reinterpret_cast<const short8*>(
            l2wb + (size_t)(n0 + col)*FFD + kq*32 + quad*8);
        acc = __builtin_amdgcn_mfma_f32_16x16x32_bf16(af[kq], bf, acc, 0, 0, 0);
      }
      #pragma unroll
      for (int r = 0; r < 4; r++)
        xb[quad*4 + r][n0 + col] = f2bf(acc[r] + attnS[quad*4 + r][n0 + col]);
    }
  }
  __syncthreads();
  {
    short8 af[4];
    #pragma unroll
    for (int kq = 0; kq < 4; kq++)
      af[kq] = *reinterpret_cast<const short8*>(&xb[col][quad*8 + kq*32]);
    #pragma unroll
    for (int j = 0; j < 2; j++) {
      const int n0 = w*32 + j*16;
      const float bia = fb[n0 + col];
      float4v acc = (float4v){bia, bia, bia, bia};
      #pragma unroll
      for (int kq = 0; kq < 4; kq++) {
        const short8 bf = *reinterpret_cast<const short8*>(
            fwb + (size_t)(n0 + col)*CH + kq*32 + quad*8);
        acc = __builtin_amdgcn_mfma_f32_16x16x32_bf16(af[kq], bf, acc, 0, 0, 0);
      }
      #pragma unroll
      for (int r = 0; r < 4; r++)
        outp[(size_t)(qbase + quad*4 + r)*CH + n0 + col] = fmaxf(acc[r], 0.0f);
    }
  }
}

// ---------------------------------------------------------------------------
extern "C" void kernel_launch(void* const* d_in, const int* in_sizes, int n_in,
                              void* d_out, int out_size, void* d_ws, size_t ws_size,
                              hipStream_t stream) {
  const float* vfeat  = (const float*)d_in[0];
  const float* vcoord = (const float*)d_in[1];
  const float* qcoord = (const float*)d_in[2];
  const int*   kidx   = (const int*)  d_in[3];
  const float* n1g    = (const float*)d_in[4];
  const float* n1b    = (const float*)d_in[5];
  const float* qpw    = (const float*)d_in[6];
  const float* qpb    = (const float*)d_in[7];
  const float* kpw    = (const float*)d_in[8];
  const float* kpb    = (const float*)d_in[9];
  const float* in_w   = (const float*)d_in[10];
  const float* in_b   = (const float*)d_in[11];
  const float* out_w  = (const float*)d_in[12];
  const float* out_b  = (const float*)d_in[13];
  const float* n2g    = (const float*)d_in[14];
  const float* n2b    = (const float*)d_in[15];
  const float* l1w    = (const float*)d_in[16];
  const float* l1b    = (const float*)d_in[17];
  const float* l2w    = (const float*)d_in[18];
  const float* l2b    = (const float*)d_in[19];
  const float* fw     = (const float*)d_in[20];
  const float* fb     = (const float*)d_in[21];
  float* out = (float*)d_out;

  unsigned short* KVh = (unsigned short*)d_ws;               // 8*NVOX*32 shorts (20.5 MB)
  __hip_bfloat16* Eb = (__hip_bfloat16*)(KVh + (size_t)8*NVOX*32);  // 98304 bf16 epi weights
  float* qb = (float*)(Eb + 98304);                          // NQRY*CH f32
  float* cx = qb + (size_t)NQRY*CH;                          // NQRY*CH f32
  unsigned* sink = (unsigned*)(cx + (size_t)NQRY*CH);        // 1 dword DCE guard

  k_main<<<NKV + NEB + NQRY/16, 256, 0, stream>>>(
      vfeat, vcoord, n1g, n1b, kpw, kpb, in_w, in_b,
      out_w, l1w, l2w, fw, qcoord, qpw, qpb, KVh, Eb, qb);
  k_attn<<<(NQRY/8)*8, 256, 0, stream>>>(KVh, qb, kidx, cx, sink);
  k_epi <<<NQRY/16, 256, 0, stream>>>(cx, Eb, out_b, n2g, n2b, l1b, l2b, fb, out);
}